// Round 2
// baseline (426.239 us; speedup 1.0000x reference)
//
#include <hip/hip_runtime.h>
#include <hip/hip_fp16.h>

// Problem constants
#define B_     8
#define NCAM   5
#define J_     15
#define H_     128
#define W_     240
#define NB     128000             // bins = 80*80*20
#define HW_    (H_ * W_)          // 30720
// Overlapping row-pair f16 image: dword[y][x] = (f16 v(y,x), f16 v(y+1,x)),
// y in 0..H-2. Any clamped 2x2 window = dwords (yc,xc),(yc,xc+1): ONE
// ds_read2_b32 per sample, all 8B useful.
#define OV_ROWS (H_ - 1)          // 127
#define OV_DW   (OV_ROWS * W_)    // 30480 dwords
#define SMEM_BYTES (OV_DW * 4)    // 121920 B -> 1 block/CU (16 waves)
#define OV_G4   (OV_DW / 4)       // 7620 uint4 groups
#define TPB    1024
#define NCHUNK 4                  // 480 blocks
#define BPB    (NB / NCHUNK)      // 32000 bins per block
#define ITEMS  32                 // 32000/1024 = 31.25; last item partial
#define NBJ    (B_ * J_)          // 120
#define NBLK   (NBJ * NCHUNK)     // 480
// R2: explicit software pipeline. Weights prefetched 2 groups ahead (~700cy
// cover, L2/L3), LDS reads 1 group ahead (~350cy cover). R1 evidence: all
// pipes idle (VALU 18%, LDS ~37%, HBM 6%) at 52 VGPRs -> latency-bound.
#define GRP    4
#define NGRP   (ITEMS / GRP)      // 8

typedef __fp16 fp16x2 __attribute__((ext_vector_type(2)));

__device__ __forceinline__ unsigned int pkrtz(float lo, float hi) {
    fp16x2 h = __builtin_amdgcn_cvt_pkrtz(lo, hi);  // v_cvt_pkrtz_f16_f32
    return __builtin_bit_cast(unsigned int, h);
}

// f32 dot of two f16 pairs: v_dot2_f32_f16. Accumulates in f32 (more precise
// than the old hmul2/hfma2 chain which rounded products to f16).
__device__ __forceinline__ float fdot2(unsigned int d, unsigned int w, float c) {
#if __has_builtin(__builtin_amdgcn_fdot2)
    return __builtin_amdgcn_fdot2(__builtin_bit_cast(fp16x2, d),
                                  __builtin_bit_cast(fp16x2, w), c, false);
#else
    __half2 p = __hmul2(__builtin_bit_cast(__half2, d),
                        __builtin_bit_cast(__half2, w));
    return c + __low2float(p) + __high2float(p);
#endif
}

// Bilinear weights, padding_mode='zeros' validity folded into clamped 2x2
// window (validated R1/R4). Camera-mean 1/5 folded into weights.
// addr16 = yc*W + xc (max 30478, fits u16);
// w0pk=(0.2*a0*b0, 0.2*a0*b1) for col xc, w1pk likewise for xc+1 — pair over
// rows (yc, yc+1) matches the overlapping row-pair LDS dword layout.
__device__ __forceinline__ void bilinear_rec(float gx, float gy,
                                             unsigned int& addr,
                                             unsigned int& w0pk,
                                             unsigned int& w1pk) {
    const float ix = (gx + 1.0f) * (0.5f * (W_ - 1));
    const float iy = (gy + 1.0f) * (0.5f * (H_ - 1));
    const float x0f = floorf(ix);
    const float y0f = floorf(iy);
    const float wx1 = ix - x0f, wx0 = 1.0f - wx1;
    const float wy1 = iy - y0f, wy0 = 1.0f - wy1;
    const int x0 = (int)x0f;
    const int y0 = (int)y0f;
    const int xc = min(max(x0, 0), W_ - 2);
    const int yc = min(max(y0, 0), H_ - 2);
    const float vx0 = (x0 >= 0  && x0 <= W_ - 1) ? wx0 : 0.0f;
    const float vx1 = (x0 >= -1 && x0 <= W_ - 2) ? wx1 : 0.0f;
    const float vy0 = (y0 >= 0  && y0 <= H_ - 1) ? wy0 : 0.0f;
    const float vy1 = (y0 >= -1 && y0 <= H_ - 2) ? wy1 : 0.0f;
    const bool xhi = (x0 == W_ - 1);
    const bool xlo = (x0 == -1);
    const bool yhi = (y0 == H_ - 1);
    const bool ylo = (y0 == -1);
    const float a0 = (xhi ? 0.0f : vx0) + (xlo ? vx1 : 0.0f);
    const float a1 = (xhi ? vx0 : 0.0f) + (xlo ? 0.0f : vx1);
    const float b0 = (yhi ? 0.0f : vy0) + (ylo ? vy1 : 0.0f);
    const float b1 = (yhi ? vy0 : 0.0f) + (ylo ? 0.0f : vy1);
    addr = (unsigned int)(yc * W_ + xc);
    w0pk = pkrtz(0.2f * (a0 * b0), 0.2f * (a0 * b1));
    w1pk = pkrtz(0.2f * (a1 * b0), 0.2f * (a1 * b1));
}

__global__ __launch_bounds__(256) void weights_kernel(
    const float* __restrict__ sgrid,          // [NCAM, NB, 2]
    unsigned short* __restrict__ addr16,      // [NCAM*NB]
    uint2* __restrict__ wpk)                  // [NCAM*NB]
{
    const int i = blockIdx.x * 256 + threadIdx.x;
    if (i >= NCAM * NB) return;
    const float2 g = ((const float2*)sgrid)[i];
    unsigned int a, w0, w1;
    bilinear_rec(g.x, g.y, a, w0, w1);
    addr16[i] = (unsigned short)a;
    wpk[i] = make_uint2(w0, w1);
}

// Stage f32 HxW image as overlapping row-pair f16 dwords (121.9 KB).
__device__ __forceinline__ void stage_overlap(const float* __restrict__ img,
                                              unsigned int* s_img, int tid) {
    const float4* __restrict__ src4 = (const float4*)img;  // 60 groups per row
    uint4* dst = (uint4*)s_img;
    for (int gi = tid; gi < OV_G4; gi += TPB) {
        const int y  = gi / 60;
        const int xg = gi - y * 60;
        const float4 t = src4[y * 60 + xg];        // row y
        const float4 b = src4[y * 60 + 60 + xg];   // row y+1
        uint4 d;
        d.x = pkrtz(t.x, b.x);
        d.y = pkrtz(t.y, b.y);
        d.z = pkrtz(t.z, b.z);
        d.w = pkrtz(t.w, b.w);
        dst[gi] = d;
    }
}

// Weight-record group: GRP items' addr + packed weights (12 VGPRs at GRP=4).
struct WRec {
    unsigned int a[GRP];
    uint2 w[GRP];
};

// Load one group's weights. Tail item (ITEMS-1) gets zero weights on lanes
// past BPB (garbage*0 == 0), keeping the pipeline branch-free.
template <int G>
__device__ __forceinline__ void load_grp(const unsigned short* __restrict__ ap,
                                         const uint2* __restrict__ wp,
                                         int tid, bool tail_ok, WRec& W) {
#pragma unroll
    for (int u = 0; u < GRP; ++u) {
        constexpr int it = G * GRP;  // + u below (keep indices static)
        const int r = (it + u) * TPB + tid;
        if (it + u < ITEMS - 1 || tail_ok) {
            W.a[u] = ap[r];
            W.w[u] = wp[r];
        } else {
            W.a[u] = 0;
            W.w[u] = make_uint2(0u, 0u);
        }
    }
}

__device__ __forceinline__ void read_grp(const unsigned int* s_img, const WRec& W,
                                         unsigned int* d0, unsigned int* d1) {
#pragma unroll
    for (int u = 0; u < GRP; ++u) {
        const unsigned int* base = s_img + W.a[u];
        d0[u] = base[0];        // ds_read2_b32: (v(yc,xc), v(yc+1,xc)) ...
        d1[u] = base[1];        // ... and col xc+1
    }
}

template <int G>
__device__ __forceinline__ void fma_grp(const WRec& W, const unsigned int* d0,
                                        const unsigned int* d1, float* acc) {
#pragma unroll
    for (int u = 0; u < GRP; ++u) {
        const float t = fdot2(d0[u], W.w[u].x, acc[G * GRP + u]);
        acc[G * GRP + u] = fdot2(d1[u], W.w[u].y, t);
    }
}

#define COPY_W(dst, src) do { _Pragma("unroll") \
    for (int _u = 0; _u < GRP; ++_u) { (dst).a[_u] = (src).a[_u]; (dst).w[_u] = (src).w[_u]; } } while (0)
#define COPY_D(dst, src) do { _Pragma("unroll") \
    for (int _u = 0; _u < GRP; ++_u) (dst)[_u] = (src)[_u]; } while (0)

// 1 block/CU (121.9 KB LDS, 16 waves). VGPR cap 128 (4 waves/EU): pipeline
// needs ~90 live regs (32 acc + 3 WRec + 2 LDS groups).
__global__ __launch_bounds__(TPB, 4) void project_kernel(
    const float* __restrict__ hm,             // [B, NCAM, J, H, W]
    const unsigned short* __restrict__ addr16,
    const uint2* __restrict__ wpk,
    float* __restrict__ out)                  // [B, J, NB]
{
    extern __shared__ unsigned int s_img[];   // OV_DW dwords
    const int tid   = threadIdx.x;
    // bj-major mapping: same-bj blocks at bids bj+120k; 120%8==0 -> same XCD,
    // so all 4 chunks of a (b,j) share one XCD's L2 for the staged images.
    const int bj    = blockIdx.x % NBJ;
    const int chunk = blockIdx.x / NBJ;
    const int b     = bj / J_;
    const int j     = bj % J_;
    const int bin0  = chunk * BPB;
    // last item: r = 31*1024+tid < 32000  <=>  tid < 256 (wave-uniform)
    const bool tail_ok = (tid < BPB - (ITEMS - 1) * TPB);

    float acc[ITEMS];
#pragma unroll
    for (int it = 0; it < ITEMS; ++it) acc[it] = 0.0f;

    for (int n = 0; n < NCAM; ++n) {
        __syncthreads();
        stage_overlap(hm + (((size_t)b * NCAM + n) * J_ + j) * HW_, s_img, tid);
        __syncthreads();
        const unsigned short* __restrict__ ap = addr16 + n * NB + bin0;
        const uint2* __restrict__ wp = wpk + n * NB + bin0;

        // 3-stage pipeline over NGRP groups:
        //   g: load W[g+2] (global) | read D[g+1] (LDS) | dot W[g],D[g] (VALU)
        WRec Wa, Wb, Wc;
        unsigned int d0a[GRP], d1a[GRP], d0b[GRP], d1b[GRP];
        load_grp<0>(ap, wp, tid, tail_ok, Wa);
        load_grp<1>(ap, wp, tid, tail_ok, Wb);
        read_grp(s_img, Wa, d0a, d1a);
#pragma unroll
        for (int g = 0; g < NGRP; ++g) {
            if (g + 2 < NGRP) {
                switch (g) {  // static template index per unrolled iteration
                    case 0: load_grp<2>(ap, wp, tid, tail_ok, Wc); break;
                    case 1: load_grp<3>(ap, wp, tid, tail_ok, Wc); break;
                    case 2: load_grp<4>(ap, wp, tid, tail_ok, Wc); break;
                    case 3: load_grp<5>(ap, wp, tid, tail_ok, Wc); break;
                    case 4: load_grp<6>(ap, wp, tid, tail_ok, Wc); break;
                    case 5: load_grp<7>(ap, wp, tid, tail_ok, Wc); break;
                }
            }
            if (g + 1 < NGRP) read_grp(s_img, Wb, d0b, d1b);
            switch (g) {
                case 0: fma_grp<0>(Wa, d0a, d1a, acc); break;
                case 1: fma_grp<1>(Wa, d0a, d1a, acc); break;
                case 2: fma_grp<2>(Wa, d0a, d1a, acc); break;
                case 3: fma_grp<3>(Wa, d0a, d1a, acc); break;
                case 4: fma_grp<4>(Wa, d0a, d1a, acc); break;
                case 5: fma_grp<5>(Wa, d0a, d1a, acc); break;
                case 6: fma_grp<6>(Wa, d0a, d1a, acc); break;
                case 7: fma_grp<7>(Wa, d0a, d1a, acc); break;
            }
            COPY_W(Wa, Wb);
            COPY_W(Wb, Wc);
            COPY_D(d0a, d0b);
            COPY_D(d1a, d1b);
        }
    }

    float* __restrict__ o = out + (size_t)bj * NB + bin0;
#pragma unroll
    for (int it = 0; it < ITEMS; ++it) {
        const int r = it * TPB + tid;
        if (r < BPB) o[r] = fminf(fmaxf(acc[it], 0.0f), 1.0f);  // 1/5 in weights
    }
}

// Fallback (tiny ws): R1-style f32-LDS kernel, inline weights. 600 blocks.
#define FB_SMEM   (HW_ * 4)
#define FB_NCHUNK 5
#define FB_BPB    (NB / FB_NCHUNK)   // 25600
#define FB_ITEMS  (FB_BPB / TPB)     // 25
__global__ __launch_bounds__(TPB) void project_fallback(
    const float* __restrict__ hm,
    const float* __restrict__ sgrid,
    float* __restrict__ out)
{
    extern __shared__ float s_f32[];
    const int tid   = threadIdx.x;
    const int bj    = blockIdx.x % NBJ;
    const int chunk = blockIdx.x / NBJ;
    const int b     = bj / J_;
    const int j     = bj % J_;
    const int bin0  = chunk * FB_BPB;

    float acc[FB_ITEMS];
#pragma unroll
    for (int it = 0; it < FB_ITEMS; ++it) acc[it] = 0.0f;

    for (int n = 0; n < NCAM; ++n) {
        __syncthreads();
        const float4* __restrict__ src =
            (const float4*)(hm + (((size_t)b * NCAM + n) * J_ + j) * HW_);
        float4* dst = (float4*)s_f32;
        for (int i = tid; i < HW_ / 4; i += TPB) dst[i] = src[i];
        __syncthreads();
        const float2* __restrict__ g2 = (const float2*)sgrid + n * NB + bin0;
#pragma unroll
        for (int it = 0; it < FB_ITEMS; ++it) {
            const float2 g = g2[it * TPB + tid];
            const float ix = (g.x + 1.0f) * (0.5f * (W_ - 1));
            const float iy = (g.y + 1.0f) * (0.5f * (H_ - 1));
            const float x0f = floorf(ix), y0f = floorf(iy);
            const float wx1 = ix - x0f, wx0 = 1.0f - wx1;
            const float wy1 = iy - y0f, wy0 = 1.0f - wy1;
            const int x0 = (int)x0f, y0 = (int)y0f;
            const int xc = min(max(x0, 0), W_ - 2);
            const int yc = min(max(y0, 0), H_ - 2);
            const float vx0 = (x0 >= 0  && x0 <= W_ - 1) ? wx0 : 0.0f;
            const float vx1 = (x0 >= -1 && x0 <= W_ - 2) ? wx1 : 0.0f;
            const float vy0 = (y0 >= 0  && y0 <= H_ - 1) ? wy0 : 0.0f;
            const float vy1 = (y0 >= -1 && y0 <= H_ - 2) ? wy1 : 0.0f;
            const bool xhi = (x0 == W_ - 1), xlo = (x0 == -1);
            const bool yhi = (y0 == H_ - 1), ylo = (y0 == -1);
            const float a0 = (xhi ? 0.0f : vx0) + (xlo ? vx1 : 0.0f);
            const float a1 = (xhi ? vx0 : 0.0f) + (xlo ? 0.0f : vx1);
            const float b0 = (yhi ? 0.0f : vy0) + (ylo ? vy1 : 0.0f);
            const float b1 = (yhi ? vy0 : 0.0f) + (ylo ? 0.0f : vy1);
            const float* r0 = s_f32 + (yc * W_ + xc);
            acc[it] += b0 * (a0 * r0[0] + a1 * r0[1])
                     + b1 * (a0 * r0[W_] + a1 * r0[W_ + 1]);
        }
    }
    float* __restrict__ o = out + (size_t)bj * NB + bin0;
#pragma unroll
    for (int it = 0; it < FB_ITEMS; ++it)
        o[it * TPB + tid] = fminf(fmaxf(acc[it] * 0.2f, 0.0f), 1.0f);
}

extern "C" void kernel_launch(void* const* d_in, const int* in_sizes, int n_in,
                              void* d_out, int out_size, void* d_ws, size_t ws_size,
                              hipStream_t stream) {
    const float* hm = (const float*)d_in[0];   // [8,5,15,128,240] f32
    const float* sg = (const float*)d_in[1];   // [5,128000,2] f32
    float* out = (float*)d_out;                // [8,15,128000] f32

    (void)hipFuncSetAttribute((const void*)project_kernel,
                              hipFuncAttributeMaxDynamicSharedMemorySize, SMEM_BYTES);
    (void)hipFuncSetAttribute((const void*)project_fallback,
                              hipFuncAttributeMaxDynamicSharedMemorySize, FB_SMEM);

    const size_t addr_bytes = (size_t)NCAM * NB * sizeof(unsigned short); // 1.28 MB
    const size_t wpk_bytes  = (size_t)NCAM * NB * sizeof(uint2);          // 5.12 MB
    if (ws_size >= addr_bytes + wpk_bytes) {
        unsigned short* addr16 = (unsigned short*)d_ws;
        uint2* wpk = (uint2*)((char*)d_ws + addr_bytes);
        weights_kernel<<<(NCAM * NB + 255) / 256, 256, 0, stream>>>(sg, addr16, wpk);
        project_kernel<<<NBLK, TPB, SMEM_BYTES, stream>>>(hm, addr16, wpk, out);
    } else {
        project_fallback<<<NBJ * FB_NCHUNK, TPB, FB_SMEM, stream>>>(hm, sg, out);
    }
}

// Round 3
// 408.736 us; speedup vs baseline: 1.0428x; 1.0428x over previous
//
#include <hip/hip_runtime.h>
#include <hip/hip_fp16.h>

// Problem constants
#define B_     8
#define NCAM   5
#define J_     15
#define H_     128
#define W_     240
#define NB     128000             // bins = 80*80*20
#define HW_    (H_ * W_)          // 30720
// Overlapping row-pair f16 image: dword[y][x] = (f16 v(y,x), f16 v(y+1,x)),
// y in 0..H-2. Any clamped 2x2 window = dwords (yc,xc),(yc,xc+1): ONE
// ds_read2_b32 per sample, all 8B useful.
#define OV_ROWS (H_ - 1)          // 127
#define OV_DW   (OV_ROWS * W_)    // 30480 dwords
#define SMEM_BYTES (OV_DW * 4)    // 121920 B -> 1 block/CU (16 waves)
#define OV_G4   (OV_DW / 4)       // 7620 uint4 groups
#define TPB    1024
#define NCHUNK 4                  // 480 blocks
#define BPB    (NB / NCHUNK)      // 32000 bins per block
#define ITEMS  32                 // 32000/1024 = 31.25; last item partial
#define NBJ    (B_ * J_)          // 120
#define NBLK   (NBJ * NCHUNK)     // 480
// R3: flat batch-of-8 phases (16 global loads -> 8 ds_read2 -> 16 dots),
// plain local arrays, static indices, NO rotation (R2's rotating buffers
// spilled to scratch: WRITE_SIZE 60->530 MB). waves_per_eu(4,4) pins the
// true occupancy (dynamic LDS caps us at 1 block/CU = 4 waves/EU, which the
// compiler can't see) so the allocator uses the full 128-VGPR budget.
#define GRP    8
#define NGRP   (ITEMS / GRP)      // 4

typedef __fp16 fp16x2 __attribute__((ext_vector_type(2)));

__device__ __forceinline__ unsigned int pkrtz(float lo, float hi) {
    fp16x2 h = __builtin_amdgcn_cvt_pkrtz(lo, hi);  // v_cvt_pkrtz_f16_f32
    return __builtin_bit_cast(unsigned int, h);
}

// f32 dot of two f16 pairs: v_dot2_f32_f16. Accumulates in f32 (more precise
// than the hmul2/hfma2 chain which rounded products to f16).
__device__ __forceinline__ float fdot2(unsigned int d, unsigned int w, float c) {
#if __has_builtin(__builtin_amdgcn_fdot2)
    return __builtin_amdgcn_fdot2(__builtin_bit_cast(fp16x2, d),
                                  __builtin_bit_cast(fp16x2, w), c, false);
#else
    __half2 p = __hmul2(__builtin_bit_cast(__half2, d),
                        __builtin_bit_cast(__half2, w));
    return c + __low2float(p) + __high2float(p);
#endif
}

// Bilinear weights, padding_mode='zeros' validity folded into clamped 2x2
// window (validated R1/R4). Camera-mean 1/5 folded into weights.
// addr16 = yc*W + xc (max 30478, fits u16);
// w0pk=(0.2*a0*b0, 0.2*a0*b1) for col xc, w1pk likewise for xc+1 — pair over
// rows (yc, yc+1) matches the overlapping row-pair LDS dword layout.
__device__ __forceinline__ void bilinear_rec(float gx, float gy,
                                             unsigned int& addr,
                                             unsigned int& w0pk,
                                             unsigned int& w1pk) {
    const float ix = (gx + 1.0f) * (0.5f * (W_ - 1));
    const float iy = (gy + 1.0f) * (0.5f * (H_ - 1));
    const float x0f = floorf(ix);
    const float y0f = floorf(iy);
    const float wx1 = ix - x0f, wx0 = 1.0f - wx1;
    const float wy1 = iy - y0f, wy0 = 1.0f - wy1;
    const int x0 = (int)x0f;
    const int y0 = (int)y0f;
    const int xc = min(max(x0, 0), W_ - 2);
    const int yc = min(max(y0, 0), H_ - 2);
    const float vx0 = (x0 >= 0  && x0 <= W_ - 1) ? wx0 : 0.0f;
    const float vx1 = (x0 >= -1 && x0 <= W_ - 2) ? wx1 : 0.0f;
    const float vy0 = (y0 >= 0  && y0 <= H_ - 1) ? wy0 : 0.0f;
    const float vy1 = (y0 >= -1 && y0 <= H_ - 2) ? wy1 : 0.0f;
    const bool xhi = (x0 == W_ - 1);
    const bool xlo = (x0 == -1);
    const bool yhi = (y0 == H_ - 1);
    const bool ylo = (y0 == -1);
    const float a0 = (xhi ? 0.0f : vx0) + (xlo ? vx1 : 0.0f);
    const float a1 = (xhi ? vx0 : 0.0f) + (xlo ? 0.0f : vx1);
    const float b0 = (yhi ? 0.0f : vy0) + (ylo ? vy1 : 0.0f);
    const float b1 = (yhi ? vy0 : 0.0f) + (ylo ? 0.0f : vy1);
    addr = (unsigned int)(yc * W_ + xc);
    w0pk = pkrtz(0.2f * (a0 * b0), 0.2f * (a0 * b1));
    w1pk = pkrtz(0.2f * (a1 * b0), 0.2f * (a1 * b1));
}

__global__ __launch_bounds__(256) void weights_kernel(
    const float* __restrict__ sgrid,          // [NCAM, NB, 2]
    unsigned short* __restrict__ addr16,      // [NCAM*NB]
    uint2* __restrict__ wpk)                  // [NCAM*NB]
{
    const int i = blockIdx.x * 256 + threadIdx.x;
    if (i >= NCAM * NB) return;
    const float2 g = ((const float2*)sgrid)[i];
    unsigned int a, w0, w1;
    bilinear_rec(g.x, g.y, a, w0, w1);
    addr16[i] = (unsigned short)a;
    wpk[i] = make_uint2(w0, w1);
}

// Stage f32 HxW image as overlapping row-pair f16 dwords (121.9 KB).
__device__ __forceinline__ void stage_overlap(const float* __restrict__ img,
                                              unsigned int* s_img, int tid) {
    const float4* __restrict__ src4 = (const float4*)img;  // 60 groups per row
    uint4* dst = (uint4*)s_img;
    for (int gi = tid; gi < OV_G4; gi += TPB) {
        const int y  = gi / 60;
        const int xg = gi - y * 60;
        const float4 t = src4[y * 60 + xg];        // row y
        const float4 b = src4[y * 60 + 60 + xg];   // row y+1
        uint4 d;
        d.x = pkrtz(t.x, b.x);
        d.y = pkrtz(t.y, b.y);
        d.z = pkrtz(t.z, b.z);
        d.w = pkrtz(t.w, b.w);
        dst[gi] = d;
    }
}

// 1 block/CU (121.9 KB LDS, 16 waves = 4 waves/EU). waves_per_eu(4,4) tells
// the compiler this IS the occupancy -> full 128-VGPR budget for scheduling.
__global__ __launch_bounds__(TPB)
__attribute__((amdgpu_waves_per_eu(4, 4)))
void project_kernel(
    const float* __restrict__ hm,             // [B, NCAM, J, H, W]
    const unsigned short* __restrict__ addr16,
    const uint2* __restrict__ wpk,
    float* __restrict__ out)                  // [B, J, NB]
{
    extern __shared__ unsigned int s_img[];   // OV_DW dwords
    const int tid   = threadIdx.x;
    // bj-major mapping: same-bj blocks at bids bj+120k; 120%8==0 -> same XCD,
    // so all 4 chunks of a (b,j) share one XCD's L2 for the staged images.
    const int bj    = blockIdx.x % NBJ;
    const int chunk = blockIdx.x / NBJ;
    const int b     = bj / J_;
    const int j     = bj % J_;
    const int bin0  = chunk * BPB;
    // last item: r = 31*1024+tid < 32000  <=>  tid < 256 (wave-uniform)
    const bool tail_ok = (tid < BPB - (ITEMS - 1) * TPB);

    float acc[ITEMS];
#pragma unroll
    for (int it = 0; it < ITEMS; ++it) acc[it] = 0.0f;

    for (int n = 0; n < NCAM; ++n) {
        __syncthreads();
        stage_overlap(hm + (((size_t)b * NCAM + n) * J_ + j) * HW_, s_img, tid);
        __syncthreads();
        const unsigned short* __restrict__ ap = addr16 + n * NB + bin0;
        const uint2* __restrict__ wp = wpk + n * NB + bin0;

        // Batch-of-8 phases: 16 independent global loads in flight, then 8
        // ds_read2, then 16 f32 dots. Flat arrays, static indices (rule #20).
#pragma unroll
        for (int g = 0; g < NGRP; ++g) {
            unsigned int a[GRP];
            uint2 w[GRP];
#pragma unroll
            for (int u = 0; u < GRP; ++u) {
                const int it = g * GRP + u;            // compile-time constant
                const int r = it * TPB + tid;
                if (it < ITEMS - 1 || tail_ok) {
                    a[u] = ap[r];
                    w[u] = wp[r];
                } else {                               // tail: garbage*0 == 0
                    a[u] = 0;
                    w[u] = make_uint2(0u, 0u);
                }
            }
            unsigned int d0[GRP], d1[GRP];
#pragma unroll
            for (int u = 0; u < GRP; ++u) {
                const unsigned int* base = s_img + a[u];
                d0[u] = base[0];    // ds_read2_b32: (v(yc,xc), v(yc+1,xc)) ...
                d1[u] = base[1];    // ... and col xc+1
            }
#pragma unroll
            for (int u = 0; u < GRP; ++u) {
                const float t = fdot2(d0[u], w[u].x, acc[g * GRP + u]);
                acc[g * GRP + u] = fdot2(d1[u], w[u].y, t);
            }
        }
    }

    float* __restrict__ o = out + (size_t)bj * NB + bin0;
#pragma unroll
    for (int it = 0; it < ITEMS; ++it) {
        const int r = it * TPB + tid;
        if (r < BPB) o[r] = fminf(fmaxf(acc[it], 0.0f), 1.0f);  // 1/5 in weights
    }
}

// Fallback (tiny ws): R1-style f32-LDS kernel, inline weights. 600 blocks.
#define FB_SMEM   (HW_ * 4)
#define FB_NCHUNK 5
#define FB_BPB    (NB / FB_NCHUNK)   // 25600
#define FB_ITEMS  (FB_BPB / TPB)     // 25
__global__ __launch_bounds__(TPB) void project_fallback(
    const float* __restrict__ hm,
    const float* __restrict__ sgrid,
    float* __restrict__ out)
{
    extern __shared__ float s_f32[];
    const int tid   = threadIdx.x;
    const int bj    = blockIdx.x % NBJ;
    const int chunk = blockIdx.x / NBJ;
    const int b     = bj / J_;
    const int j     = bj % J_;
    const int bin0  = chunk * FB_BPB;

    float acc[FB_ITEMS];
#pragma unroll
    for (int it = 0; it < FB_ITEMS; ++it) acc[it] = 0.0f;

    for (int n = 0; n < NCAM; ++n) {
        __syncthreads();
        const float4* __restrict__ src =
            (const float4*)(hm + (((size_t)b * NCAM + n) * J_ + j) * HW_);
        float4* dst = (float4*)s_f32;
        for (int i = tid; i < HW_ / 4; i += TPB) dst[i] = src[i];
        __syncthreads();
        const float2* __restrict__ g2 = (const float2*)sgrid + n * NB + bin0;
#pragma unroll
        for (int it = 0; it < FB_ITEMS; ++it) {
            const float2 g = g2[it * TPB + tid];
            const float ix = (g.x + 1.0f) * (0.5f * (W_ - 1));
            const float iy = (g.y + 1.0f) * (0.5f * (H_ - 1));
            const float x0f = floorf(ix), y0f = floorf(iy);
            const float wx1 = ix - x0f, wx0 = 1.0f - wx1;
            const float wy1 = iy - y0f, wy0 = 1.0f - wy1;
            const int x0 = (int)x0f, y0 = (int)y0f;
            const int xc = min(max(x0, 0), W_ - 2);
            const int yc = min(max(y0, 0), H_ - 2);
            const float vx0 = (x0 >= 0  && x0 <= W_ - 1) ? wx0 : 0.0f;
            const float vx1 = (x0 >= -1 && x0 <= W_ - 2) ? wx1 : 0.0f;
            const float vy0 = (y0 >= 0  && y0 <= H_ - 1) ? wy0 : 0.0f;
            const float vy1 = (y0 >= -1 && y0 <= H_ - 2) ? wy1 : 0.0f;
            const bool xhi = (x0 == W_ - 1), xlo = (x0 == -1);
            const bool yhi = (y0 == H_ - 1), ylo = (y0 == -1);
            const float a0 = (xhi ? 0.0f : vx0) + (xlo ? vx1 : 0.0f);
            const float a1 = (xhi ? vx0 : 0.0f) + (xlo ? 0.0f : vx1);
            const float b0 = (yhi ? 0.0f : vy0) + (ylo ? vy1 : 0.0f);
            const float b1 = (yhi ? vy0 : 0.0f) + (ylo ? 0.0f : vy1);
            const float* r0 = s_f32 + (yc * W_ + xc);
            acc[it] += b0 * (a0 * r0[0] + a1 * r0[1])
                     + b1 * (a0 * r0[W_] + a1 * r0[W_ + 1]);
        }
    }
    float* __restrict__ o = out + (size_t)bj * NB + bin0;
#pragma unroll
    for (int it = 0; it < FB_ITEMS; ++it)
        o[it * TPB + tid] = fminf(fmaxf(acc[it] * 0.2f, 0.0f), 1.0f);
}

extern "C" void kernel_launch(void* const* d_in, const int* in_sizes, int n_in,
                              void* d_out, int out_size, void* d_ws, size_t ws_size,
                              hipStream_t stream) {
    const float* hm = (const float*)d_in[0];   // [8,5,15,128,240] f32
    const float* sg = (const float*)d_in[1];   // [5,128000,2] f32
    float* out = (float*)d_out;                // [8,15,128000] f32

    (void)hipFuncSetAttribute((const void*)project_kernel,
                              hipFuncAttributeMaxDynamicSharedMemorySize, SMEM_BYTES);
    (void)hipFuncSetAttribute((const void*)project_fallback,
                              hipFuncAttributeMaxDynamicSharedMemorySize, FB_SMEM);

    const size_t addr_bytes = (size_t)NCAM * NB * sizeof(unsigned short); // 1.28 MB
    const size_t wpk_bytes  = (size_t)NCAM * NB * sizeof(uint2);          // 5.12 MB
    if (ws_size >= addr_bytes + wpk_bytes) {
        unsigned short* addr16 = (unsigned short*)d_ws;
        uint2* wpk = (uint2*)((char*)d_ws + addr_bytes);
        weights_kernel<<<(NCAM * NB + 255) / 256, 256, 0, stream>>>(sg, addr16, wpk);
        project_kernel<<<NBLK, TPB, SMEM_BYTES, stream>>>(hm, addr16, wpk, out);
    } else {
        project_fallback<<<NBJ * FB_NCHUNK, TPB, FB_SMEM, stream>>>(hm, sg, out);
    }
}